// Round 13
// baseline (172.401 us; speedup 1.0000x reference)
//
#include <hip/hip_runtime.h>
#include <hip/hip_bf16.h>

typedef __bf16 bf16x8 __attribute__((ext_vector_type(8)));
typedef float f32x4 __attribute__((ext_vector_type(4)));
typedef unsigned short u16x8 __attribute__((ext_vector_type(8)));

#define GN    1024
#define BATCH 64
#define CIN   256
#define COUT  256
#define NG    4                      // one g-quad per block
#define A_ELEMS (BATCH * CIN)        // per-g: 16384 ushorts = 32 KB
#define WSLICE  2048                 // 16 o-rows x 32k x 4B

#define G_AS __attribute__((address_space(1)))
#define L_AS __attribute__((address_space(3)))

static __device__ __forceinline__ void gload16(const void* g, void* l) {
  __builtin_amdgcn_global_load_lds((const G_AS void*)g, (L_AS void*)l, 16, 0, 0);
}

static __device__ __forceinline__ void vmwait(int n) {
  if (n == 0)       asm volatile("s_waitcnt vmcnt(0)"  ::: "memory");
  else if (n == 2)  asm volatile("s_waitcnt vmcnt(2)"  ::: "memory");
  else if (n == 18) asm volatile("s_waitcnt vmcnt(18)" ::: "memory");
}

static __device__ __forceinline__ ushort f2bf(float f) {
  __hip_bfloat16 h = __float2bfloat16(f);
  return *reinterpret_cast<ushort*>(&h);
}

// ---------------------------------------------------------------------------
// Kernel 1 (unchanged, R11): x[b][i][g] f32 -> xT[b][g][i^((b&7)<<3)] bf16
// ---------------------------------------------------------------------------
__global__ __launch_bounds__(256) void k_transpose_convert(
    const float* __restrict__ x, ushort* __restrict__ xT)
{
  __shared__ float tile[128][65];  // [i][g^key]
  const int g0 = blockIdx.x * 64;
  const int i0 = blockIdx.y * 128;
  const int b  = blockIdx.z;
  const int t  = threadIdx.x;
  const int a  = t & 15;
  const int r  = t >> 4;
  const int keyb = (b & 7) << 3;

  const float* xb = x + (size_t)b * CIN * GN;
#pragma unroll
  for (int p = 0; p < 8; ++p) {
    int i = p * 16 + r;
    float4 v = *reinterpret_cast<const float4*>(
        &xb[(size_t)(i0 + i) * GN + g0 + a * 4]);
    int c = (a * 4) ^ (((i >> 5) & 1) << 4);
    tile[i][c + 0] = v.x;
    tile[i][c + 1] = v.y;
    tile[i][c + 2] = v.z;
    tile[i][c + 3] = v.w;
  }
  __syncthreads();

  ushort* xTb = xT + (size_t)b * GN * CIN;
#pragma unroll
  for (int p = 0; p < 4; ++p) {
    int g = p * 16 + r;
    u16x8 u;
#pragma unroll
    for (int k = 0; k < 8; ++k) {
      int il = a * 8 + k;
      u[k] = f2bf(tile[il][g ^ (((il >> 5) & 1) << 4)]);
    }
    int isw = (i0 + a * 8) ^ keyb;
    *reinterpret_cast<u16x8*>(&xTb[(size_t)(g0 + g) * CIN + isw]) = u;
  }
}

// ---------------------------------------------------------------------------
// FUSED-OUTPUT GEMM: block owns g-quad [4q,4q+4); writes out[b][o][g] DIRECTLY
// as float4 over the quad (16B of each 64B line; the 4 sibling quad-blocks of
// every line share one XCD-L2 via the bid->q swizzle; all 256 blocks are
// co-resident at 1/CU so partial lines merge in write-back L2).
// Structure: o-tile outer, g inner; acc[m][gi]. A-quad (4x32KB, staged ONCE
// from xT via DMA, one barrier total). W: per-wave ring-2 of 2KB slices
// (16 o-rows x 32k), counted vmcnt {2 steady, 18 post-store, 0 final}.
// ---------------------------------------------------------------------------
__global__ __launch_bounds__(256, 1) void k_fused_gemm(
    const ushort* __restrict__ xT, const float* __restrict__ W,
    const float* __restrict__ bias, float* __restrict__ out)
{
  __shared__ __align__(16) unsigned char lds[4 * A_ELEMS * 2 + 4 * 2 * WSLICE]; // 144 KB
  ushort* lA        = (ushort*)lds;   // row (b*4+gi): [64b][4g][256i]
  unsigned char* lW = lds + 4 * A_ELEMS * 2;

  const int tid  = threadIdx.x;
  const int wave = tid >> 6;
  const int lane = tid & 63;

  // bid -> quad id: 4 sibling quads (same 64B out-line) on same XCD (bid%8),
  // bijective for 256 blocks.
  const int bid    = blockIdx.x;
  const int q      = 4 * ((bid & 7) + 8 * (bid >> 5)) + ((bid >> 3) & 3);
  const int g_base = q * 4;

  const int arow = lane & 15;
  const int qq   = lane >> 4;

  unsigned char* lWw = lW + wave * (2 * WSLICE);

  // stage W slice s = n*32 + gi*8 + ks (2 KB = 2 issues of 8 rows x 128B)
  auto stage_slice = [&](int s) {
    const int n = s >> 5, gi = (s >> 3) & 3, ks = s & 7;
    unsigned char* ldb = lWw + (s & 1) * WSLICE;
    const unsigned char* gb = (const unsigned char*)W
        + (((size_t)(g_base + gi) * COUT + 64 * wave + n * 16 + (lane >> 3)) * CIN) * 4
        + ks * 128 + (((lane & 7) * 16) ^ (((lane >> 3) & 7) << 4));
    gload16(gb, ldb);
    gload16(gb + 8 * CIN * 4, ldb + 1024);
  };

  // ---- prologue ----
  stage_slice(0);
  stage_slice(1);

  float bvv[4][4];  // [gi][n]
#pragma unroll
  for (int gi = 0; gi < 4; ++gi)
#pragma unroll
    for (int n = 0; n < 4; ++n)
      bvv[gi][n] = bias[(g_base + gi) * COUT + 64 * wave + n * 16 + arow];
  __builtin_amdgcn_sched_barrier(0);

  // A-quad: wave w stages b-rows [16w,16w+16); per b: 2 issues x 1KB
  // (1KB = 2 consecutive g-rows of xT, landing linearly in lA).
#pragma unroll
  for (int j = 0; j < 32; ++j) {
    const int b    = 16 * wave + (j >> 1);
    const int half = j & 1;
    const ushort* src = xT + ((size_t)b * GN + g_base + 2 * half) * CIN + lane * 8;
    gload16(src, lA + (b * 4 + 2 * half) * CIN);
  }
  __syncthreads();  // drains everything; slices 0,1 + A resident

#pragma unroll
  for (int n = 0; n < 4; ++n) {
    f32x4 acc[4][4];  // [m][gi]
#pragma unroll
    for (int m = 0; m < 4; ++m)
#pragma unroll
      for (int gi = 0; gi < 4; ++gi)
        acc[m][gi] = {0.f, 0.f, 0.f, 0.f};

#pragma unroll
    for (int gi = 0; gi < 4; ++gi) {
#pragma unroll
      for (int ks = 0; ks < 8; ++ks) {
        const int s = n * 32 + gi * 8 + ks;
        if (s == 127)                        vmwait(0);
        else if ((s & 31) < 2 && s >= 32)    vmwait(18);
        else                                 vmwait(2);
        __builtin_amdgcn_sched_barrier(0);

        unsigned char* wb = lWw + (s & 1) * WSLICE;
        const int key = (arow & 7) << 4;
        float4 f0 = *reinterpret_cast<const float4*>(
            wb + arow * 128 + ((qq * 32) ^ key));
        float4 f1 = *reinterpret_cast<const float4*>(
            wb + arow * 128 + ((qq * 32 + 16) ^ key));

        bf16x8 afr[4];
        const int i0 = ks * 32 + qq * 8;
#pragma unroll
        for (int m = 0; m < 4; ++m) {
          int row = m * 16 + arow;
          afr[m] = *reinterpret_cast<const bf16x8*>(
              &lA[(row * 4 + gi) * CIN + (i0 ^ ((row & 7) << 3))]);
        }

        asm volatile("s_waitcnt lgkmcnt(0)" ::: "memory");
        __builtin_amdgcn_sched_barrier(0);
        if (s + 2 < 128) stage_slice(s + 2);
        __builtin_amdgcn_sched_barrier(0);

        bf16x8 bfr;
        bfr[0] = (__bf16)f0.x; bfr[1] = (__bf16)f0.y;
        bfr[2] = (__bf16)f0.z; bfr[3] = (__bf16)f0.w;
        bfr[4] = (__bf16)f1.x; bfr[5] = (__bf16)f1.y;
        bfr[6] = (__bf16)f1.z; bfr[7] = (__bf16)f1.w;

        __builtin_amdgcn_s_setprio(1);
#pragma unroll
        for (int m = 0; m < 4; ++m)
          acc[m][gi] = __builtin_amdgcn_mfma_f32_16x16x32_bf16(
              afr[m], bfr, acc[m][gi], 0, 0, 0);
        __builtin_amdgcn_s_setprio(0);
      }
    }

    // ---- stores for this o-tile: float4 over the g-quad ----
    const int o = 64 * wave + n * 16 + arow;
#pragma unroll
    for (int m = 0; m < 4; ++m) {
#pragma unroll
      for (int j = 0; j < 4; ++j) {
        const int b = m * 16 + 4 * qq + j;
        float4 v;
        v.x = acc[m][0][j] + bvv[0][n];
        v.y = acc[m][1][j] + bvv[1][n];
        v.z = acc[m][2][j] + bvv[2][n];
        v.w = acc[m][3][j] + bvv[3][n];
        *reinterpret_cast<float4*>(
            &out[((size_t)b * COUT + o) * GN + g_base]) = v;
      }
    }
    __builtin_amdgcn_sched_barrier(0);
  }
}

// ---------------------------------------------------------------------------
extern "C" void kernel_launch(void* const* d_in, const int* in_sizes, int n_in,
                              void* d_out, int out_size, void* d_ws, size_t ws_size,
                              hipStream_t stream) {
  const float* x  = (const float*)d_in[0];
  const float* W  = (const float*)d_in[1];
  const float* bs = (const float*)d_in[2];
  float* out      = (float*)d_out;

  ushort* xT = (ushort*)d_ws;  // 33.5 MB (ws proven >= 67 MB in prior rounds)

  dim3 grid1(GN / 64, CIN / 128, BATCH);
  k_transpose_convert<<<grid1, 256, 0, stream>>>(x, xT);
  k_fused_gemm<<<GN / NG, 256, 0, stream>>>(xT, W, bs, out);
}

// Round 14
// 111.769 us; speedup vs baseline: 1.5425x; 1.5425x over previous
//
#include <hip/hip_runtime.h>
#include <hip/hip_bf16.h>

typedef __bf16 bf16x8 __attribute__((ext_vector_type(8)));
typedef float f32x4 __attribute__((ext_vector_type(4)));
typedef unsigned short u16x8 __attribute__((ext_vector_type(8)));

#define GN    1024
#define BATCH 64
#define CIN   256
#define COUT  256
#define NG    4                      // g's per persistent block (k2)
#define A_ELEMS (BATCH * CIN)        // 16384 ushorts = 32 KB
#define WSLICE  8192                 // per wave, per buffer: 64 o-rows x 32 k x 4B

#define G_AS __attribute__((address_space(1)))
#define L_AS __attribute__((address_space(3)))

static __device__ __forceinline__ void gload16(const void* g, void* l) {
  __builtin_amdgcn_global_load_lds((const G_AS void*)g, (L_AS void*)l, 16, 0, 0);
}

static __device__ __forceinline__ ushort f2bf(float f) {
  __hip_bfloat16 h = __float2bfloat16(f);
  return *reinterpret_cast<ushort*>(&h);
}
static __device__ __forceinline__ float bf2f(ushort u) {
  uint v = (uint)u << 16;
  return *reinterpret_cast<float*>(&v);
}

// ---------------------------------------------------------------------------
// Kernel 1 (R11): x[b][i][g] f32 -> xT[b][g][i^((b&7)<<3)] bf16
// Tile 64 g x 128 i; 2048 blocks; 33 KB LDS (~4 blocks/CU).
// ---------------------------------------------------------------------------
__global__ __launch_bounds__(256) void k_transpose_convert(
    const float* __restrict__ x, ushort* __restrict__ xT)
{
  __shared__ float tile[128][65];  // [i][g^key]
  const int g0 = blockIdx.x * 64;
  const int i0 = blockIdx.y * 128;
  const int b  = blockIdx.z;
  const int t  = threadIdx.x;
  const int a  = t & 15;
  const int r  = t >> 4;
  const int keyb = (b & 7) << 3;

  const float* xb = x + (size_t)b * CIN * GN;
#pragma unroll
  for (int p = 0; p < 8; ++p) {
    int i = p * 16 + r;
    float4 v = *reinterpret_cast<const float4*>(
        &xb[(size_t)(i0 + i) * GN + g0 + a * 4]);
    int c = (a * 4) ^ (((i >> 5) & 1) << 4);
    tile[i][c + 0] = v.x;
    tile[i][c + 1] = v.y;
    tile[i][c + 2] = v.z;
    tile[i][c + 3] = v.w;
  }
  __syncthreads();

  ushort* xTb = xT + (size_t)b * GN * CIN;
#pragma unroll
  for (int p = 0; p < 4; ++p) {
    int g = p * 16 + r;
    u16x8 u;
#pragma unroll
    for (int k = 0; k < 8; ++k) {
      int il = a * 8 + k;
      u[k] = f2bf(tile[il][g ^ (((il >> 5) & 1) << 4)]);
    }
    int isw = (i0 + a * 8) ^ keyb;
    *reinterpret_cast<u16x8*>(&xTb[(size_t)(g0 + g) * CIN + isw]) = u;
  }
}

// ---------------------------------------------------------------------------
// Kernel 2: PERSISTENT per-group GEMM (R6 structure; measured ~57 us via the
// R9 double-launch probe = ~93% of its 335 MB streaming floor).
// ---------------------------------------------------------------------------
__global__ __launch_bounds__(256) void k_group_gemm(
    const ushort* __restrict__ xT, const float* __restrict__ W,
    const float* __restrict__ bias, float* __restrict__ out,
    ushort* __restrict__ outT, int use_ws)
{
  __shared__ __align__(16) unsigned char lds[2 * A_ELEMS * 2 + 4 * 2 * WSLICE]; // 128 KB
  ushort* lA        = (ushort*)lds;
  unsigned char* lW = lds + 2 * A_ELEMS * 2;

  const int tid  = threadIdx.x;
  const int wave = tid >> 6;
  const int lane = tid & 63;
  const int g_base = blockIdx.x * NG;

  const int arow = lane & 15;
  const int colk = (lane >> 4) * 32;
  const int kq   = (lane >> 4) << 3;
  const int oc   = 64 * wave + arow;

  unsigned char* lWw = lW + wave * (2 * WSLICE);
  const int swz_src = ((lane & 7) ^ (lane >> 3)) << 4;
  const int wrow    = lane >> 3;

  auto stage_a = [&](int gg, int ab) {
    ushort* base = lA + ab * A_ELEMS;
#pragma unroll
    for (int j = 0; j < 8; ++j) {
      int b = 16 * wave + 2 * j + (lane >> 5);
      const ushort* gsrc = xT + ((size_t)b * GN + gg) * CIN + (lane & 31) * 8;
      gload16(gsrc, base + (16 * wave + 2 * j) * CIN);
    }
  };
  auto stage_w = [&](const float* wgp, int ks, int buf) {
    unsigned char* ldb = lWw + buf * WSLICE;
    const unsigned char* gb = (const unsigned char*)wgp + (size_t)ks * 128 + swz_src;
#pragma unroll
    for (int j = 0; j < 8; ++j) {
      gload16(gb + (size_t)(8 * j + wrow) * (CIN * 4), ldb + j * 1024);
    }
  };

  // ---- prologue: bias preload (16 loads), A(g0), W0, W1 ----
  float bvv[NG][4];
#pragma unroll
  for (int gi = 0; gi < NG; ++gi)
#pragma unroll
    for (int n = 0; n < 4; ++n)
      bvv[gi][n] = bias[(g_base + gi) * COUT + oc + n * 16];
  __builtin_amdgcn_sched_barrier(0);

  stage_a(g_base, 0);
  __builtin_amdgcn_sched_barrier(0);
  {
    const float* wg0 = W + ((size_t)g_base * COUT + 64 * wave) * CIN;
    stage_w(wg0, 0, 0);
    __builtin_amdgcn_sched_barrier(0);
    stage_w(wg0, 1, 1);
    __builtin_amdgcn_sched_barrier(0);
  }
  asm volatile("s_waitcnt vmcnt(8)" ::: "memory");
  __builtin_amdgcn_sched_barrier(0);
  __builtin_amdgcn_s_barrier();

#pragma unroll
  for (int gi = 0; gi < NG; ++gi) {
    const int g = g_base + gi;
    const ushort* lAc = lA + (gi & 1) * A_ELEMS;
    const float* wgp  = W + ((size_t)g * COUT + 64 * wave) * CIN;

    f32x4 acc[4][4];
#pragma unroll
    for (int m = 0; m < 4; ++m)
#pragma unroll
      for (int n = 0; n < 4; ++n)
        acc[m][n] = {0.f, 0.f, 0.f, 0.f};

#pragma unroll
    for (int ks = 0; ks < 8; ++ks) {
      if (gi < NG - 1) {
        if (ks == 6) { asm volatile("s_waitcnt vmcnt(16)" ::: "memory"); }
        else         { asm volatile("s_waitcnt vmcnt(8)"  ::: "memory"); }
      } else {
        if (ks == 7) { asm volatile("s_waitcnt vmcnt(0)"  ::: "memory"); }
        else         { asm volatile("s_waitcnt vmcnt(8)"  ::: "memory"); }
      }
      __builtin_amdgcn_sched_barrier(0);

      unsigned char* wb = lWw + (ks & 1) * WSLICE;
      const int key = (arow & 7) << 4;

      float4 f[4][2];
#pragma unroll
      for (int n = 0; n < 4; ++n) {
        int rr = n * 16 + arow;
        f[n][0] = *reinterpret_cast<const float4*>(wb + rr * 128 + (colk ^ key));
        f[n][1] = *reinterpret_cast<const float4*>(wb + rr * 128 + ((colk + 16) ^ key));
      }
      bf16x8 afr[4];
      const int i0 = ks * 32 + kq;
#pragma unroll
      for (int m = 0; m < 4; ++m) {
        int row = m * 16 + arow;
        afr[m] = *reinterpret_cast<const bf16x8*>(
            &lAc[row * CIN + (i0 ^ ((row & 7) << 3))]);
      }

      asm volatile("s_waitcnt lgkmcnt(0)" ::: "memory");
      __builtin_amdgcn_sched_barrier(0);
      if (ks < 6) stage_w(wgp, ks + 2, ks & 1);
      if (ks == 4 && gi < NG - 1) stage_a(g + 1, (gi & 1) ^ 1);
      __builtin_amdgcn_sched_barrier(0);

      bf16x8 bfr[4];
#pragma unroll
      for (int n = 0; n < 4; ++n) {
        bfr[n][0] = (__bf16)f[n][0].x; bfr[n][1] = (__bf16)f[n][0].y;
        bfr[n][2] = (__bf16)f[n][0].z; bfr[n][3] = (__bf16)f[n][0].w;
        bfr[n][4] = (__bf16)f[n][1].x; bfr[n][5] = (__bf16)f[n][1].y;
        bfr[n][6] = (__bf16)f[n][1].z; bfr[n][7] = (__bf16)f[n][1].w;
      }

      __builtin_amdgcn_s_setprio(1);
#pragma unroll
      for (int m = 0; m < 4; ++m)
#pragma unroll
        for (int n = 0; n < 4; ++n)
          acc[m][n] = __builtin_amdgcn_mfma_f32_16x16x32_bf16(
              afr[m], bfr[n], acc[m][n], 0, 0, 0);
      __builtin_amdgcn_s_setprio(0);
    }

    // ---- epilogue for g ----
    if (use_ws) {
#pragma unroll
      for (int m = 0; m < 4; ++m) {
#pragma unroll
        for (int n = 0; n < 4; ++n) {
          int o = oc + n * 16;
#pragma unroll
          for (int j = 0; j < 4; ++j) {
            int b = m * 16 + ((lane >> 4) << 2) + j;
            __hip_bfloat16 h = __float2bfloat16(acc[m][n][j] + bvv[gi][n]);
            outT[((size_t)b * GN + g) * COUT + o] = *reinterpret_cast<ushort*>(&h);
          }
        }
      }
    } else {
#pragma unroll
      for (int m = 0; m < 4; ++m) {
#pragma unroll
        for (int n = 0; n < 4; ++n) {
          int o = oc + n * 16;
#pragma unroll
          for (int j = 0; j < 4; ++j) {
            int b = m * 16 + ((lane >> 4) << 2) + j;
            out[((size_t)b * COUT + o) * GN + g] = acc[m][n][j] + bvv[gi][n];
          }
        }
      }
    }
    __builtin_amdgcn_sched_barrier(0);

    if (gi < NG - 1) {
      const float* wgn = W + ((size_t)(g + 1) * COUT + 64 * wave) * CIN;
      stage_w(wgn, 0, 0);
      __builtin_amdgcn_sched_barrier(0);
      stage_w(wgn, 1, 1);
      __builtin_amdgcn_sched_barrier(0);
      asm volatile("s_waitcnt vmcnt(8)" ::: "memory");
      __builtin_amdgcn_sched_barrier(0);
      __builtin_amdgcn_s_barrier();
    }
  }
}

// ---------------------------------------------------------------------------
// Kernel 3 (R11): transpose outT[b][g][o] bf16 -> out[b][o][g] f32
// Tile 64 g x 128 o; 2048 blocks; 33 KB LDS.
// ---------------------------------------------------------------------------
__global__ __launch_bounds__(256) void k_transpose_out(
    const ushort* __restrict__ outT, float* __restrict__ out)
{
  __shared__ float tile[128][65];  // [o][g^key]
  const int g0 = blockIdx.x * 64;
  const int o0 = blockIdx.y * 128;
  const int b  = blockIdx.z;
  const int t  = threadIdx.x;
  const int a  = t & 15;
  const int r  = t >> 4;

  const ushort* src = outT + (size_t)b * GN * COUT;
#pragma unroll
  for (int p = 0; p < 4; ++p) {
    int g = p * 16 + r;
    u16x8 u = *reinterpret_cast<const u16x8*>(
        &src[(size_t)(g0 + g) * COUT + o0 + a * 8]);
#pragma unroll
    for (int k = 0; k < 8; ++k) {
      int ol = a * 8 + k;
      tile[ol][g ^ (((ol >> 5) & 1) << 4)] = bf2f(u[k]);
    }
  }
  __syncthreads();

  float* dst = out + (size_t)b * COUT * GN;
#pragma unroll
  for (int p = 0; p < 8; ++p) {
    int o = p * 16 + r;
    int c = (a * 4) ^ (((o >> 5) & 1) << 4);
    float4 v;
    v.x = tile[o][c + 0];
    v.y = tile[o][c + 1];
    v.z = tile[o][c + 2];
    v.w = tile[o][c + 3];
    *reinterpret_cast<float4*>(
        &dst[(size_t)(o0 + o) * GN + g0 + a * 4]) = v;
  }
}

// ---------------------------------------------------------------------------
extern "C" void kernel_launch(void* const* d_in, const int* in_sizes, int n_in,
                              void* d_out, int out_size, void* d_ws, size_t ws_size,
                              hipStream_t stream) {
  const float* x  = (const float*)d_in[0];
  const float* W  = (const float*)d_in[1];
  const float* bs = (const float*)d_in[2];
  float* out      = (float*)d_out;

  const size_t xT_elems = (size_t)BATCH * GN * CIN;
  const size_t oT_elems = (size_t)BATCH * GN * COUT;
  const bool use_ws = ws_size >= (xT_elems + oT_elems) * sizeof(ushort);

  ushort* xT   = (ushort*)d_ws;
  ushort* outT = xT + xT_elems;

  dim3 grid1(GN / 64, CIN / 128, BATCH);
  k_transpose_convert<<<grid1, 256, 0, stream>>>(x, xT);
  k_group_gemm<<<GN / NG, 256, 0, stream>>>(xT, W, bs, out,
                                            use_ws ? outT : nullptr,
                                            use_ws ? 1 : 0);
  if (use_ws) {
    dim3 grid3(GN / 64, COUT / 128, BATCH);
    k_transpose_out<<<grid3, 256, 0, stream>>>(outT, out);
  }
}